// Round 11
// baseline (441.534 us; speedup 1.0000x reference)
//
#include <hip/hip_runtime.h>

#define TOK   32768
#define DM    768
#define KDIM  768
#define LSEQ  4096
#define NC    64
#define CL    64
#define NCHAIN 6144

typedef __bf16 bf16x8 __attribute__((ext_vector_type(8)));
typedef float  f32x4  __attribute__((ext_vector_type(4)));
typedef unsigned short u16;
typedef unsigned int u32;

__device__ __forceinline__ u16 f2bf(float f) {
  unsigned u = __builtin_bit_cast(unsigned, f);
  u += 0x7fffu + ((u >> 16) & 1u);
  return (u16)(u >> 16);
}
__device__ __forceinline__ float bf2f(u32 h) {
  unsigned u = (h & 0xffffu) << 16;
  return __builtin_bit_cast(float, u);
}

#define GLOAD_LDS16(g, l) __builtin_amdgcn_global_load_lds( \
    (const __attribute__((address_space(1))) void*)(g),     \
    (__attribute__((address_space(3))) void*)(l), 16, 0, 0)

// ---------------- fp32 -> bf16 weight convert ----------------
__global__ void cvt_k(const float* __restrict__ src, u16* __restrict__ dst, int n) {
  int i = blockIdx.x * 256 + threadIdx.x;
  if (i < n) dst[i] = f2bf(src[i]);
}

// ---------------- fp32 -> bf16 with zero padding ----------------
__global__ void cvt_pad_k(const float* __restrict__ src, u16* __restrict__ dst,
                          int rows, int cols, int dcols, int n) {
  int i = blockIdx.x * 256 + threadIdx.x;
  if (i >= n) return;
  int r = i / dcols, c = i % dcols;
  dst[i] = (r < rows && c < cols) ? f2bf(src[r * cols + c]) : (u16)0;
}

// ---------------- RMSNorm: x (fp32) -> xn (bf16), float4 path ----------------
__global__ __launch_bounds__(192)
void rmsnorm_k(const float* __restrict__ x, const float* __restrict__ w,
               u16* __restrict__ xnb) {
  long t = blockIdx.x;
  int tid = threadIdx.x;
  float4 v = ((const float4*)x)[t * 192 + tid];
  float s = v.x * v.x + v.y * v.y + v.z * v.z + v.w * v.w;
#pragma unroll
  for (int o = 32; o; o >>= 1) s += __shfl_down(s, o, 64);
  __shared__ float red[3];
  if ((tid & 63) == 0) red[tid >> 6] = s;
  __syncthreads();
  float sc = rsqrtf((red[0] + red[1] + red[2]) * (1.f / 768.f) + 1e-6f);
  float4 ww = ((const float4*)w)[tid];
  ushort4 o;
  o.x = f2bf(v.x * sc * ww.x);
  o.y = f2bf(v.y * sc * ww.y);
  o.z = f2bf(v.z * sc * ww.z);
  o.w = f2bf(v.w * sc * ww.w);
  ((ushort4*)xnb)[t * 192 + tid] = o;
}

// ---------------- 512-thread BM=256 BN=256 BK=32 GEMM, 2-buf, 8 waves ----------
// C[m][n] = sum_k A[m][k]*B[n][k]; A,B bf16 row-major (lda/ldb), K % 32 == 0.
// 8 waves 2M x 4N; per-wave output 128x64 (acc[8][4] = 128 VGPR). Rationale
// (LDS-service arithmetic, m134): per block-K-step this shape issues 96
// ds_read_b128 (~1150 cy) feeding 256 MFMA (~1240 cy) -> balanced, vs the
// 64x64/wave shape's 768 cy LDS per 620 cy MFMA (LDS-dominated). 2.7x better
// FLOP per LDS-cycle via bigger per-wave tile.
// __launch_bounds__(512,2): 2 waves/SIMD -> 256-VGPR budget, guarantees
// acc[8][4] stays in registers (rounds 2/3 failed via silent spill).
// LDS 2 x (16KB A + 16KB B) = 64KB, 1 block/CU.
// Conflict swizzle both-sides (rule 21): phys 16B slot = logical ^ ((row>>1)&3).
// Schedule (round-6): STAGE(t+1) before compute(t); one __syncthreads/K-step.
// Block swizzle (T1): xcd = bid&7 owns a contiguous row-panel band.
// EPI: 0 fp32 C; 1 in_proj (conv+silu->o0, silu(z)->o1).
template <int EPI>
__global__ __launch_bounds__(512, 2)
void gemm512(const u16* __restrict__ A, int lda,
             const u16* __restrict__ B, int ldb, int K,
             int GX, int RPX,
             float* __restrict__ C,
             const float* __restrict__ w0, const float* __restrict__ w1,
             u16* __restrict__ o0, u16* __restrict__ o1) {
  __shared__ __align__(16) u16 smA[2 * 8192];
  __shared__ __align__(16) u16 smB[2 * 8192];
  const int tid = threadIdx.x;
  const int lane = tid & 63;
  const int wid = tid >> 6;   // 0..7

  const int bid = blockIdx.x;
  const int xcd = bid & 7;
  const int p = bid >> 3;
  const int colp = p % GX;
  const int rowp = xcd * RPX + p / GX;
  const long rowBase = (long)rowp * 256;
  const long colBase = (long)colp * 256;

  const int wm = wid >> 2;          // 0..1 -> row block 128
  const int wn = wid & 3;           // 0..3 -> col block 64
  const int lr = lane & 15;
  const int kc = lane >> 4;
  const int kcs = kc ^ ((lr >> 1) & 3);   // swizzled 16B slot for ds_read

  // staging (pre-swizzled source): A,B each 1024 chunks of 16B; this thread
  // owns chunks tid and tid+512. chunk c -> row c>>2, slot (c&3)^((c>>3)&3).
  const int c1 = tid + 512;
  const u16* gA0 = A + (rowBase + (tid >> 2)) * lda + ((tid & 3) ^ ((tid >> 3) & 3)) * 8;
  const u16* gA1 = A + (rowBase + (c1 >> 2)) * lda + ((c1 & 3) ^ ((c1 >> 3) & 3)) * 8;
  const u16* gB0 = B + (colBase + (tid >> 2)) * ldb + ((tid & 3) ^ ((tid >> 3) & 3)) * 8;
  const u16* gB1 = B + (colBase + (c1 >> 2)) * ldb + ((c1 & 3) ^ ((c1 >> 3) & 3)) * 8;

  f32x4 acc[8][4] = {};
  const int NT = K >> 5;

  auto STAGE = [&](int buf, int kt) {
    u16* bA = smA + buf * 8192;
    u16* bB = smB + buf * 8192;
    GLOAD_LDS16(gA0 + kt, &bA[tid * 8]);
    GLOAD_LDS16(gA1 + kt, &bA[c1 * 8]);
    GLOAD_LDS16(gB0 + kt, &bB[tid * 8]);
    GLOAD_LDS16(gB1 + kt, &bB[c1 * 8]);
  };

  STAGE(0, 0);
  __syncthreads();

  for (int t = 0; t < NT; ++t) {
    if (t + 1 < NT) STAGE((t + 1) & 1, (t + 1) << 5);   // loads fly during compute
    const u16* cA = smA + (t & 1) * 8192;
    const u16* cB = smB + (t & 1) * 8192;
    bf16x8 af[8], bfr[4];
#pragma unroll
    for (int m = 0; m < 8; ++m)
      af[m] = *(const bf16x8*)&cA[(wm * 128 + m * 16 + lr) * 32 + kcs * 8];
#pragma unroll
    for (int n = 0; n < 4; ++n)
      bfr[n] = *(const bf16x8*)&cB[(wn * 64 + n * 16 + lr) * 32 + kcs * 8];
#pragma unroll
    for (int m = 0; m < 8; ++m)
#pragma unroll
      for (int n = 0; n < 4; ++n)
        acc[m][n] = __builtin_amdgcn_mfma_f32_16x16x32_bf16(af[m], bfr[n], acc[m][n], 0, 0, 0);
    __syncthreads();   // drains next-tile loads + this tile's LDS reads
  }

#pragma unroll
  for (int m = 0; m < 8; ++m)
#pragma unroll
    for (int n = 0; n < 4; ++n)
#pragma unroll
      for (int j = 0; j < 4; ++j) {
        long grow = rowBase + wm * 128 + m * 16 + kc * 4 + j;
        long gcol = colBase + wn * 64 + n * 16 + lr;
        float v = acc[m][n][j];
        if (EPI == 0) {
          C[grow * DM + gcol] = v;
        } else {
          if (gcol < DM) {
            float t = v * w0[gcol] + w1[gcol];
            o0[grow * DM + gcol] = f2bf(t / (1.f + __expf(-t)));
          } else {
            o1[grow * DM + (gcol - DM)] = f2bf(v / (1.f + __expf(-v)));
          }
        }
      }
}

// ---------------- BK=32 MFMA GEMM (x_proj / dt), 3-buffer, counted vmcnt ----------
// Round-7 proven kernel. EPI: 2 dt (bias + fast softplus -> o0 bf16, stride DM);
// 3 x_proj (cols<64 -> o0 ld 64; cols 48/49 -> C fp32 at t*2+{0,1}).
template <int EPI>
__global__ __launch_bounds__(256)
void gemm32(const u16* __restrict__ A, int lda,
            const u16* __restrict__ B, int ldb, int K,
            int GX, int RPX,
            float* __restrict__ C,
            const float* __restrict__ w0,
            u16* __restrict__ o0) {
  __shared__ __align__(16) u16 smA[3 * 4096];
  __shared__ __align__(16) u16 smB[3 * 4096];
  const int tid = threadIdx.x;
  const int lane = tid & 63;
  const int wid = tid >> 6;

  const int bid = blockIdx.x;
  const int xcd = bid & 7;
  const int p = bid >> 3;
  const int colp = p % GX;
  const int rowp = xcd * RPX + p / GX;
  const long rowBase = (long)rowp * 128;
  const long colBase = (long)colp * 128;

  const int wr = (wid >> 1) * 64;
  const int wc = (wid & 1) * 64;
  const int lr = lane & 15;
  const int kc = lane >> 4;
  const int kcs = kc ^ ((lr >> 1) & 3);

  const int c1 = tid + 256;
  const u16* gA0 = A + (rowBase + (tid >> 2)) * lda + ((tid & 3) ^ ((tid >> 3) & 3)) * 8;
  const u16* gA1 = A + (rowBase + (c1 >> 2)) * lda + ((c1 & 3) ^ ((c1 >> 3) & 3)) * 8;
  const u16* gB0 = B + (colBase + (tid >> 2)) * ldb + ((tid & 3) ^ ((tid >> 3) & 3)) * 8;
  const u16* gB1 = B + (colBase + (c1 >> 2)) * ldb + ((c1 & 3) ^ ((c1 >> 3) & 3)) * 8;

  f32x4 acc[4][4] = {};
  const int NT = K >> 5;

  auto STAGE = [&](int buf, int kt) {
    u16* bA = smA + buf * 4096;
    u16* bB = smB + buf * 4096;
    GLOAD_LDS16(gA0 + kt, &bA[tid * 8]);
    GLOAD_LDS16(gA1 + kt, &bA[c1 * 8]);
    GLOAD_LDS16(gB0 + kt, &bB[tid * 8]);
    GLOAD_LDS16(gB1 + kt, &bB[c1 * 8]);
  };

  STAGE(0, 0);
  STAGE(1, 32);
  asm volatile("s_waitcnt vmcnt(4)" ::: "memory");  // tile 0 landed; tile 1 in flight
  __builtin_amdgcn_s_barrier();

  for (int t = 0; t < NT; ++t) {
    const u16* cA = smA + (t % 3) * 4096;
    const u16* cB = smB + (t % 3) * 4096;
    bf16x8 af[4], bfr[4];
#pragma unroll
    for (int m = 0; m < 4; ++m)
      af[m] = *(const bf16x8*)&cA[(wr + m * 16 + lr) * 32 + kcs * 8];
#pragma unroll
    for (int n = 0; n < 4; ++n)
      bfr[n] = *(const bf16x8*)&cB[(wc + n * 16 + lr) * 32 + kcs * 8];
    if (t + 2 < NT) STAGE((t + 2) % 3, (t + 2) << 5);
#pragma unroll
    for (int m = 0; m < 4; ++m)
#pragma unroll
      for (int n = 0; n < 4; ++n)
        acc[m][n] = __builtin_amdgcn_mfma_f32_16x16x32_bf16(af[m], bfr[n], acc[m][n], 0, 0, 0);
    if (t + 1 < NT) {
      if (t + 2 < NT) asm volatile("s_waitcnt vmcnt(4) lgkmcnt(0)" ::: "memory");
      else            asm volatile("s_waitcnt vmcnt(0) lgkmcnt(0)" ::: "memory");
      __builtin_amdgcn_s_barrier();
    }
  }

#pragma unroll
  for (int m = 0; m < 4; ++m)
#pragma unroll
    for (int n = 0; n < 4; ++n)
#pragma unroll
      for (int j = 0; j < 4; ++j) {
        long grow = rowBase + wr + m * 16 + kc * 4 + j;
        long gcol = colBase + wc + n * 16 + lr;
        float v = acc[m][n][j];
        if (EPI == 2) {
          float t = v + w0[gcol];
          float d = (t > 20.f) ? t : __logf(1.f + __expf(t));
          o0[grow * DM + gcol] = f2bf(d);
        } else {  // EPI == 3
          if (gcol < 64) o0[grow * 64 + gcol] = f2bf(v);
          if (gcol == 48) C[grow * 2 + 0] = v;
          if (gcol == 49) C[grow * 2 + 1] = v;
        }
      }
}

// ---------------- selective scan (N_STATE=1), chunked 3-pass, 2 channels/thread ----
__global__ __launch_bounds__(384)
void scan1_k(const u16* __restrict__ deltab, const u16* __restrict__ xcb,
             const float* __restrict__ bmc, const float* __restrict__ A_log,
             float* __restrict__ aprod, float* __restrict__ hend) {
  int pe = threadIdx.x;
  int b = blockIdx.x, c = blockIdx.y;
  int e0 = pe * 2;
  float Ae0 = -__expf(A_log[e0]), Ae1 = -__expf(A_log[e0 + 1]);
  float ap0 = 1.f, h0 = 0.f, ap1 = 1.f, h1 = 0.f;
  long base = (long)b * LSEQ + (long)c * CL;
  for (int i = 0; i < CL; ++i) {
    long t = base + i;
    u32 dv = *(const u32*)&deltab[t * DM + e0];
    u32 xv = *(const u32*)&xcb[t * DM + e0];
    float Bm = bmc[t * 2];
    float d0 = bf2f(dv), d1 = bf2f(dv >> 16);
    float x0 = bf2f(xv), x1 = bf2f(xv >> 16);
    float a0 = __expf(d0 * Ae0), a1 = __expf(d1 * Ae1);
    ap0 *= a0; h0 = a0 * h0 + d0 * Bm * x0;
    ap1 *= a1; h1 = a1 * h1 + d1 * Bm * x1;
  }
  long chain = (long)c * NCHAIN + b * DM + e0;
  *(float2*)&aprod[chain] = make_float2(ap0, ap1);
  *(float2*)&hend[chain]  = make_float2(h0, h1);
}

__global__ __launch_bounds__(256)
void scan2_k(const float* __restrict__ aprod, const float* __restrict__ hend,
             float* __restrict__ carry) {
  int chain = blockIdx.x * 256 + threadIdx.x;
  float h = 0.f;
  for (int c = 0; c < NC; ++c) {
    carry[c * NCHAIN + chain] = h;
    h = aprod[c * NCHAIN + chain] * h + hend[c * NCHAIN + chain];
  }
}

__global__ __launch_bounds__(384)
void scan3_k(const u16* __restrict__ deltab, const u16* __restrict__ xcb,
             const float* __restrict__ bmc, const float* __restrict__ A_log,
             const float* __restrict__ Dp, const u16* __restrict__ szb,
             const float* __restrict__ carry, u16* __restrict__ ybf) {
  int pe = threadIdx.x;
  int b = blockIdx.x, c = blockIdx.y;
  int e0 = pe * 2;
  float Ae0 = -__expf(A_log[e0]), Ae1 = -__expf(A_log[e0 + 1]);
  float De0 = Dp[e0], De1 = Dp[e0 + 1];
  long chain = (long)c * NCHAIN + b * DM + e0;
  float2 hc = *(const float2*)&carry[chain];
  float h0 = hc.x, h1 = hc.y;
  long base = (long)b * LSEQ + (long)c * CL;
  for (int i = 0; i < CL; ++i) {
    long t = base + i;
    u32 dv = *(const u32*)&deltab[t * DM + e0];
    u32 xv = *(const u32*)&xcb[t * DM + e0];
    u32 sv = *(const u32*)&szb[t * DM + e0];
    float Bm = bmc[t * 2], Cc = bmc[t * 2 + 1];
    float d0 = bf2f(dv), d1 = bf2f(dv >> 16);
    float x0 = bf2f(xv), x1 = bf2f(xv >> 16);
    float a0 = __expf(d0 * Ae0), a1 = __expf(d1 * Ae1);
    h0 = a0 * h0 + d0 * Bm * x0;
    h1 = a1 * h1 + d1 * Bm * x1;
    float y0 = (h0 * Cc + De0 * x0) * bf2f(sv);
    float y1 = (h1 * Cc + De1 * x1) * bf2f(sv >> 16);
    *(u32*)&ybf[t * DM + e0] = (u32)f2bf(y0) | ((u32)f2bf(y1) << 16);
  }
}

// ---------------- launch ----------------
extern "C" void kernel_launch(void* const* d_in, const int* in_sizes, int n_in,
                              void* d_out, int out_size, void* d_ws, size_t ws_size,
                              hipStream_t stream) {
  const float* x         = (const float*)d_in[0];
  const float* rms_w     = (const float*)d_in[1];
  const float* in_proj_w = (const float*)d_in[2];
  const float* conv_w    = (const float*)d_in[3];
  const float* conv_b    = (const float*)d_in[4];
  const float* x_proj_w  = (const float*)d_in[5];
  const float* dt_proj_w = (const float*)d_in[6];
  const float* dt_proj_b = (const float*)d_in[7];
  const float* A_log     = (const float*)d_in[8];
  const float* Dp        = (const float*)d_in[9];
  const float* out_proj_w= (const float*)d_in[10];
  float* out = (float*)d_out;

  char* ws = (char*)d_ws;
  size_t off = 0;
  auto alloc = [&](size_t bytes) -> void* {
    void* p = ws + off;
    off += (bytes + 255) & ~(size_t)255;
    return p;
  };
  u16*   xnb    = (u16*)alloc((size_t)TOK * DM * 2);
  u16*   xcb    = (u16*)alloc((size_t)TOK * DM * 2);
  u16*   szb    = (u16*)alloc((size_t)TOK * DM * 2);
  u16*   ybf    = (u16*)alloc((size_t)TOK * DM * 2);
  u16*   deltab = (u16*)alloc((size_t)TOK * DM * 2);
  u16*   dbcb   = (u16*)alloc((size_t)TOK * 64 * 2);
  float* bmc    = (float*)alloc((size_t)TOK * 2 * 4);
  u16*   wInB   = (u16*)alloc((size_t)1536 * 768 * 2);
  u16*   wXpB   = (u16*)alloc((size_t)128 * 768 * 2);
  u16*   wDtB   = (u16*)alloc((size_t)768 * 64 * 2);
  u16*   wOutB  = (u16*)alloc((size_t)768 * 768 * 2);
  float* aprod  = (float*)alloc((size_t)NC * NCHAIN * 4);
  float* hend   = (float*)alloc((size_t)NC * NCHAIN * 4);
  float* carry  = (float*)alloc((size_t)NC * NCHAIN * 4);

  cvt_k<<<(1536 * 768 + 255) / 256, 256, 0, stream>>>(in_proj_w, wInB, 1536 * 768);
  cvt_k<<<(768 * 768 + 255) / 256, 256, 0, stream>>>(out_proj_w, wOutB, 768 * 768);
  cvt_pad_k<<<(128 * 768 + 255) / 256, 256, 0, stream>>>(x_proj_w, wXpB, 50, 768, 768, 128 * 768);
  cvt_pad_k<<<(768 * 64 + 255) / 256, 256, 0, stream>>>(dt_proj_w, wDtB, 768, 48, 64, 768 * 64);

  rmsnorm_k<<<TOK, 192, 0, stream>>>(x, rms_w, xnb);

  // xz = xn @ in_proj_w^T ; fused conv+silu -> xcb, silu(z) -> szb
  // grid 768 = 8 XCDs x 16 row-panels(256) x 6 col-panels(256)
  gemm512<1><<<768, 512, 0, stream>>>(
      xnb, DM, wInB, DM, KDIM, 6, 16, nullptr, conv_w, conv_b, xcb, szb);

  // dbc = xc @ x_proj_w^T (rank-50, N pad 128): delta_raw -> dbcb, Bm/C -> bmc
  gemm32<3><<<256, 256, 0, stream>>>(
      xcb, DM, wXpB, DM, KDIM, 1, 32, bmc, nullptr, dbcb);

  // delta = softplus(dbc48 @ dt_proj_w^T + dt_b) -> bf16
  gemm32<2><<<1536, 256, 0, stream>>>(
      dbcb, 64, wDtB, 64, 64, 6, 32, nullptr, dt_proj_b, deltab);

  scan1_k<<<dim3(8, NC), 384, 0, stream>>>(deltab, xcb, bmc, A_log, aprod, hend);
  scan2_k<<<NCHAIN / 256, 256, 0, stream>>>(aprod, hend, carry);
  scan3_k<<<dim3(8, NC), 384, 0, stream>>>(deltab, xcb, bmc, A_log, Dp, szb, carry, ybf);

  // out = (y * silu(z)) @ out_proj_w^T; grid 384 = 8 x 16 x 3
  gemm512<0><<<384, 512, 0, stream>>>(
      ybf, DM, wOutB, DM, KDIM, 3, 16, out, nullptr, nullptr, nullptr, nullptr);
}

// Round 12
// 328.766 us; speedup vs baseline: 1.3430x; 1.3430x over previous
//
#include <hip/hip_runtime.h>

#define TOK   32768
#define DM    768
#define KDIM  768
#define LSEQ  4096
#define NC    64
#define CL    64
#define NCHAIN 6144

typedef __bf16 bf16x8 __attribute__((ext_vector_type(8)));
typedef float  f32x4  __attribute__((ext_vector_type(4)));
typedef unsigned short u16;
typedef unsigned int u32;

__device__ __forceinline__ u16 f2bf(float f) {
  unsigned u = __builtin_bit_cast(unsigned, f);
  u += 0x7fffu + ((u >> 16) & 1u);
  return (u16)(u >> 16);
}
__device__ __forceinline__ float bf2f(u32 h) {
  unsigned u = (h & 0xffffu) << 16;
  return __builtin_bit_cast(float, u);
}

#define GLOAD_LDS16(g, l) __builtin_amdgcn_global_load_lds( \
    (const __attribute__((address_space(1))) void*)(g),     \
    (__attribute__((address_space(3))) void*)(l), 16, 0, 0)

// ---------------- fp32 -> bf16 weight convert ----------------
__global__ void cvt_k(const float* __restrict__ src, u16* __restrict__ dst, int n) {
  int i = blockIdx.x * 256 + threadIdx.x;
  if (i < n) dst[i] = f2bf(src[i]);
}

// ---------------- fp32 -> bf16 with zero padding ----------------
__global__ void cvt_pad_k(const float* __restrict__ src, u16* __restrict__ dst,
                          int rows, int cols, int dcols, int n) {
  int i = blockIdx.x * 256 + threadIdx.x;
  if (i >= n) return;
  int r = i / dcols, c = i % dcols;
  dst[i] = (r < rows && c < cols) ? f2bf(src[r * cols + c]) : (u16)0;
}

// ---------------- RMSNorm: x (fp32) -> xn (bf16), float4 path ----------------
__global__ __launch_bounds__(192)
void rmsnorm_k(const float* __restrict__ x, const float* __restrict__ w,
               u16* __restrict__ xnb) {
  long t = blockIdx.x;
  int tid = threadIdx.x;
  float4 v = ((const float4*)x)[t * 192 + tid];
  float s = v.x * v.x + v.y * v.y + v.z * v.z + v.w * v.w;
#pragma unroll
  for (int o = 32; o; o >>= 1) s += __shfl_down(s, o, 64);
  __shared__ float red[3];
  if ((tid & 63) == 0) red[tid >> 6] = s;
  __syncthreads();
  float sc = rsqrtf((red[0] + red[1] + red[2]) * (1.f / 768.f) + 1e-6f);
  float4 ww = ((const float4*)w)[tid];
  ushort4 o;
  o.x = f2bf(v.x * sc * ww.x);
  o.y = f2bf(v.y * sc * ww.y);
  o.z = f2bf(v.z * sc * ww.z);
  o.w = f2bf(v.w * sc * ww.w);
  ((ushort4*)xnb)[t * 192 + tid] = o;
}

// ---------------- 128x128 BK=32 GEMM, 2-buf, tuned for 4 blocks/CU ----------
// C[m][n] = sum_k A[m][k]*B[n][k]; A,B bf16 row-major (lda/ldb), NT = K/32 even.
// 256 thr = 4 waves (2x2), wave = 64x64 (acc[4][4] = 64 AGPR).
// Occupancy theory (R6/R7/R10 cycle accounting): structure is intra-wave-stall
// bound at 2.5-3 resident blocks; fix = 4 blocks/CU. LDS 2x16KB = 32KB (5 fit);
// register side forced under the 4-wave/SIMD line (VGPR<=64 + 64 AGPR <= 128)
// via __launch_bounds__(256,4) + lean addressing. Manual x2 K-unroll makes
// buffer selects compile-time (removes per-step index VALU).
// Conflict swizzle both-sides (rule 21): phys 16B slot = logical ^ ((row>>1)&3).
// Schedule (R6): STAGE(t+1) issued before compute(t); one __syncthreads/K-step.
// Block swizzle (T1): xcd = bid&7 owns a contiguous row-panel band.
// EPI: 0 fp32 C; 1 in_proj (conv+silu->o0, silu(z)->o1).
template <int EPI>
__global__ __launch_bounds__(256, 4)
void gemm128(const u16* __restrict__ A, int lda,
             const u16* __restrict__ B, int ldb, int K,
             int GX, int RPX,
             float* __restrict__ C,
             const float* __restrict__ w0, const float* __restrict__ w1,
             u16* __restrict__ o0, u16* __restrict__ o1) {
  __shared__ __align__(16) u16 smA[2 * 4096];
  __shared__ __align__(16) u16 smB[2 * 4096];
  const int tid = threadIdx.x;
  const int lane = tid & 63;
  const int wid = tid >> 6;

  const int bid = blockIdx.x;
  const int xcd = bid & 7;
  const int p = bid >> 3;
  const int colp = p % GX;
  const int rowp = xcd * RPX + p / GX;
  const long rowBase = (long)rowp * 128;
  const long colBase = (long)colp * 128;

  const int wr = (wid >> 1) * 64;
  const int wc = (wid & 1) * 64;
  const int lr = lane & 15;
  const int kc = lane >> 4;
  const int kcs = kc ^ ((lr >> 1) & 3);   // swizzled 16B slot for ds_read

  const int c1 = tid + 256;
  const u16* gA0 = A + (rowBase + (tid >> 2)) * lda + ((tid & 3) ^ ((tid >> 3) & 3)) * 8;
  const u16* gA1 = A + (rowBase + (c1 >> 2)) * lda + ((c1 & 3) ^ ((c1 >> 3) & 3)) * 8;
  const u16* gB0 = B + (colBase + (tid >> 2)) * ldb + ((tid & 3) ^ ((tid >> 3) & 3)) * 8;
  const u16* gB1 = B + (colBase + (c1 >> 2)) * ldb + ((c1 & 3) ^ ((c1 >> 3) & 3)) * 8;

  f32x4 acc[4][4] = {};
  const int NT = K >> 5;

  auto STAGE = [&](int buf, int kt) {
    u16* bA = smA + buf * 4096;
    u16* bB = smB + buf * 4096;
    GLOAD_LDS16(gA0 + kt, &bA[tid * 8]);
    GLOAD_LDS16(gA1 + kt, &bA[c1 * 8]);
    GLOAD_LDS16(gB0 + kt, &bB[tid * 8]);
    GLOAD_LDS16(gB1 + kt, &bB[c1 * 8]);
  };
  auto COMPUTE = [&](int buf) {
    const u16* cA = smA + buf * 4096;
    const u16* cB = smB + buf * 4096;
    bf16x8 af[4], bfr[4];
#pragma unroll
    for (int m = 0; m < 4; ++m)
      af[m] = *(const bf16x8*)&cA[(wr + m * 16 + lr) * 32 + kcs * 8];
#pragma unroll
    for (int n = 0; n < 4; ++n)
      bfr[n] = *(const bf16x8*)&cB[(wc + n * 16 + lr) * 32 + kcs * 8];
#pragma unroll
    for (int m = 0; m < 4; ++m)
#pragma unroll
      for (int n = 0; n < 4; ++n)
        acc[m][n] = __builtin_amdgcn_mfma_f32_16x16x32_bf16(af[m], bfr[n], acc[m][n], 0, 0, 0);
  };

  STAGE(0, 0);
  __syncthreads();

  // manual x2 unroll: buffer indices are compile-time constants
  for (int t = 0; t < NT; t += 2) {
    if (t + 1 < NT) STAGE(1, (t + 1) << 5);
    COMPUTE(0);
    __syncthreads();
    if (t + 2 < NT) STAGE(0, (t + 2) << 5);
    COMPUTE(1);
    __syncthreads();
  }

#pragma unroll
  for (int m = 0; m < 4; ++m)
#pragma unroll
    for (int n = 0; n < 4; ++n)
#pragma unroll
      for (int j = 0; j < 4; ++j) {
        long grow = rowBase + wr + m * 16 + kc * 4 + j;
        long gcol = colBase + wc + n * 16 + lr;
        float v = acc[m][n][j];
        if (EPI == 0) {
          C[grow * DM + gcol] = v;
        } else {
          if (gcol < DM) {
            float t2 = v * w0[gcol] + w1[gcol];
            o0[grow * DM + gcol] = f2bf(t2 / (1.f + __expf(-t2)));
          } else {
            o1[grow * DM + (gcol - DM)] = f2bf(v / (1.f + __expf(-v)));
          }
        }
      }
}

// ---------------- BK=32 MFMA GEMM (x_proj / dt), 3-buffer, counted vmcnt ----------
// Round-7 proven kernel. EPI: 2 dt (bias + fast softplus -> o0 bf16, stride DM);
// 3 x_proj (cols<64 -> o0 ld 64; cols 48/49 -> C fp32 at t*2+{0,1}).
template <int EPI>
__global__ __launch_bounds__(256)
void gemm32(const u16* __restrict__ A, int lda,
            const u16* __restrict__ B, int ldb, int K,
            int GX, int RPX,
            float* __restrict__ C,
            const float* __restrict__ w0,
            u16* __restrict__ o0) {
  __shared__ __align__(16) u16 smA[3 * 4096];
  __shared__ __align__(16) u16 smB[3 * 4096];
  const int tid = threadIdx.x;
  const int lane = tid & 63;
  const int wid = tid >> 6;

  const int bid = blockIdx.x;
  const int xcd = bid & 7;
  const int p = bid >> 3;
  const int colp = p % GX;
  const int rowp = xcd * RPX + p / GX;
  const long rowBase = (long)rowp * 128;
  const long colBase = (long)colp * 128;

  const int wr = (wid >> 1) * 64;
  const int wc = (wid & 1) * 64;
  const int lr = lane & 15;
  const int kc = lane >> 4;
  const int kcs = kc ^ ((lr >> 1) & 3);

  const int c1 = tid + 256;
  const u16* gA0 = A + (rowBase + (tid >> 2)) * lda + ((tid & 3) ^ ((tid >> 3) & 3)) * 8;
  const u16* gA1 = A + (rowBase + (c1 >> 2)) * lda + ((c1 & 3) ^ ((c1 >> 3) & 3)) * 8;
  const u16* gB0 = B + (colBase + (tid >> 2)) * ldb + ((tid & 3) ^ ((tid >> 3) & 3)) * 8;
  const u16* gB1 = B + (colBase + (c1 >> 2)) * ldb + ((c1 & 3) ^ ((c1 >> 3) & 3)) * 8;

  f32x4 acc[4][4] = {};
  const int NT = K >> 5;

  auto STAGE = [&](int buf, int kt) {
    u16* bA = smA + buf * 4096;
    u16* bB = smB + buf * 4096;
    GLOAD_LDS16(gA0 + kt, &bA[tid * 8]);
    GLOAD_LDS16(gA1 + kt, &bA[c1 * 8]);
    GLOAD_LDS16(gB0 + kt, &bB[tid * 8]);
    GLOAD_LDS16(gB1 + kt, &bB[c1 * 8]);
  };

  STAGE(0, 0);
  STAGE(1, 32);
  asm volatile("s_waitcnt vmcnt(4)" ::: "memory");  // tile 0 landed; tile 1 in flight
  __builtin_amdgcn_s_barrier();

  for (int t = 0; t < NT; ++t) {
    const u16* cA = smA + (t % 3) * 4096;
    const u16* cB = smB + (t % 3) * 4096;
    bf16x8 af[4], bfr[4];
#pragma unroll
    for (int m = 0; m < 4; ++m)
      af[m] = *(const bf16x8*)&cA[(wr + m * 16 + lr) * 32 + kcs * 8];
#pragma unroll
    for (int n = 0; n < 4; ++n)
      bfr[n] = *(const bf16x8*)&cB[(wc + n * 16 + lr) * 32 + kcs * 8];
    if (t + 2 < NT) STAGE((t + 2) % 3, (t + 2) << 5);
#pragma unroll
    for (int m = 0; m < 4; ++m)
#pragma unroll
      for (int n = 0; n < 4; ++n)
        acc[m][n] = __builtin_amdgcn_mfma_f32_16x16x32_bf16(af[m], bfr[n], acc[m][n], 0, 0, 0);
    if (t + 1 < NT) {
      if (t + 2 < NT) asm volatile("s_waitcnt vmcnt(4) lgkmcnt(0)" ::: "memory");
      else            asm volatile("s_waitcnt vmcnt(0) lgkmcnt(0)" ::: "memory");
      __builtin_amdgcn_s_barrier();
    }
  }

#pragma unroll
  for (int m = 0; m < 4; ++m)
#pragma unroll
    for (int n = 0; n < 4; ++n)
#pragma unroll
      for (int j = 0; j < 4; ++j) {
        long grow = rowBase + wr + m * 16 + kc * 4 + j;
        long gcol = colBase + wc + n * 16 + lr;
        float v = acc[m][n][j];
        if (EPI == 2) {
          float t = v + w0[gcol];
          float d = (t > 20.f) ? t : __logf(1.f + __expf(t));
          o0[grow * DM + gcol] = f2bf(d);
        } else {  // EPI == 3
          if (gcol < 64) o0[grow * 64 + gcol] = f2bf(v);
          if (gcol == 48) C[grow * 2 + 0] = v;
          if (gcol == 49) C[grow * 2 + 1] = v;
        }
      }
}

// ---------------- selective scan (N_STATE=1), chunked 3-pass, 2 channels/thread ----
__global__ __launch_bounds__(384)
void scan1_k(const u16* __restrict__ deltab, const u16* __restrict__ xcb,
             const float* __restrict__ bmc, const float* __restrict__ A_log,
             float* __restrict__ aprod, float* __restrict__ hend) {
  int pe = threadIdx.x;
  int b = blockIdx.x, c = blockIdx.y;
  int e0 = pe * 2;
  float Ae0 = -__expf(A_log[e0]), Ae1 = -__expf(A_log[e0 + 1]);
  float ap0 = 1.f, h0 = 0.f, ap1 = 1.f, h1 = 0.f;
  long base = (long)b * LSEQ + (long)c * CL;
  for (int i = 0; i < CL; ++i) {
    long t = base + i;
    u32 dv = *(const u32*)&deltab[t * DM + e0];
    u32 xv = *(const u32*)&xcb[t * DM + e0];
    float Bm = bmc[t * 2];
    float d0 = bf2f(dv), d1 = bf2f(dv >> 16);
    float x0 = bf2f(xv), x1 = bf2f(xv >> 16);
    float a0 = __expf(d0 * Ae0), a1 = __expf(d1 * Ae1);
    ap0 *= a0; h0 = a0 * h0 + d0 * Bm * x0;
    ap1 *= a1; h1 = a1 * h1 + d1 * Bm * x1;
  }
  long chain = (long)c * NCHAIN + b * DM + e0;
  *(float2*)&aprod[chain] = make_float2(ap0, ap1);
  *(float2*)&hend[chain]  = make_float2(h0, h1);
}

__global__ __launch_bounds__(256)
void scan2_k(const float* __restrict__ aprod, const float* __restrict__ hend,
             float* __restrict__ carry) {
  int chain = blockIdx.x * 256 + threadIdx.x;
  float h = 0.f;
  for (int c = 0; c < NC; ++c) {
    carry[c * NCHAIN + chain] = h;
    h = aprod[c * NCHAIN + chain] * h + hend[c * NCHAIN + chain];
  }
}

__global__ __launch_bounds__(384)
void scan3_k(const u16* __restrict__ deltab, const u16* __restrict__ xcb,
             const float* __restrict__ bmc, const float* __restrict__ A_log,
             const float* __restrict__ Dp, const u16* __restrict__ szb,
             const float* __restrict__ carry, u16* __restrict__ ybf) {
  int pe = threadIdx.x;
  int b = blockIdx.x, c = blockIdx.y;
  int e0 = pe * 2;
  float Ae0 = -__expf(A_log[e0]), Ae1 = -__expf(A_log[e0 + 1]);
  float De0 = Dp[e0], De1 = Dp[e0 + 1];
  long chain = (long)c * NCHAIN + b * DM + e0;
  float2 hc = *(const float2*)&carry[chain];
  float h0 = hc.x, h1 = hc.y;
  long base = (long)b * LSEQ + (long)c * CL;
  for (int i = 0; i < CL; ++i) {
    long t = base + i;
    u32 dv = *(const u32*)&deltab[t * DM + e0];
    u32 xv = *(const u32*)&xcb[t * DM + e0];
    u32 sv = *(const u32*)&szb[t * DM + e0];
    float Bm = bmc[t * 2], Cc = bmc[t * 2 + 1];
    float d0 = bf2f(dv), d1 = bf2f(dv >> 16);
    float x0 = bf2f(xv), x1 = bf2f(xv >> 16);
    float a0 = __expf(d0 * Ae0), a1 = __expf(d1 * Ae1);
    h0 = a0 * h0 + d0 * Bm * x0;
    h1 = a1 * h1 + d1 * Bm * x1;
    float y0 = (h0 * Cc + De0 * x0) * bf2f(sv);
    float y1 = (h1 * Cc + De1 * x1) * bf2f(sv >> 16);
    *(u32*)&ybf[t * DM + e0] = (u32)f2bf(y0) | ((u32)f2bf(y1) << 16);
  }
}

// ---------------- launch ----------------
extern "C" void kernel_launch(void* const* d_in, const int* in_sizes, int n_in,
                              void* d_out, int out_size, void* d_ws, size_t ws_size,
                              hipStream_t stream) {
  const float* x         = (const float*)d_in[0];
  const float* rms_w     = (const float*)d_in[1];
  const float* in_proj_w = (const float*)d_in[2];
  const float* conv_w    = (const float*)d_in[3];
  const float* conv_b    = (const float*)d_in[4];
  const float* x_proj_w  = (const float*)d_in[5];
  const float* dt_proj_w = (const float*)d_in[6];
  const float* dt_proj_b = (const float*)d_in[7];
  const float* A_log     = (const float*)d_in[8];
  const float* Dp        = (const float*)d_in[9];
  const float* out_proj_w= (const float*)d_in[10];
  float* out = (float*)d_out;

  char* ws = (char*)d_ws;
  size_t off = 0;
  auto alloc = [&](size_t bytes) -> void* {
    void* p = ws + off;
    off += (bytes + 255) & ~(size_t)255;
    return p;
  };
  u16*   xnb    = (u16*)alloc((size_t)TOK * DM * 2);
  u16*   xcb    = (u16*)alloc((size_t)TOK * DM * 2);
  u16*   szb    = (u16*)alloc((size_t)TOK * DM * 2);
  u16*   ybf    = (u16*)alloc((size_t)TOK * DM * 2);
  u16*   deltab = (u16*)alloc((size_t)TOK * DM * 2);
  u16*   dbcb   = (u16*)alloc((size_t)TOK * 64 * 2);
  float* bmc    = (float*)alloc((size_t)TOK * 2 * 4);
  u16*   wInB   = (u16*)alloc((size_t)1536 * 768 * 2);
  u16*   wXpB   = (u16*)alloc((size_t)128 * 768 * 2);
  u16*   wDtB   = (u16*)alloc((size_t)768 * 64 * 2);
  u16*   wOutB  = (u16*)alloc((size_t)768 * 768 * 2);
  float* aprod  = (float*)alloc((size_t)NC * NCHAIN * 4);
  float* hend   = (float*)alloc((size_t)NC * NCHAIN * 4);
  float* carry  = (float*)alloc((size_t)NC * NCHAIN * 4);

  cvt_k<<<(1536 * 768 + 255) / 256, 256, 0, stream>>>(in_proj_w, wInB, 1536 * 768);
  cvt_k<<<(768 * 768 + 255) / 256, 256, 0, stream>>>(out_proj_w, wOutB, 768 * 768);
  cvt_pad_k<<<(128 * 768 + 255) / 256, 256, 0, stream>>>(x_proj_w, wXpB, 50, 768, 768, 128 * 768);
  cvt_pad_k<<<(768 * 64 + 255) / 256, 256, 0, stream>>>(dt_proj_w, wDtB, 768, 48, 64, 768 * 64);

  rmsnorm_k<<<TOK, 192, 0, stream>>>(x, rms_w, xnb);

  // xz = xn @ in_proj_w^T ; fused conv+silu -> xcb, silu(z) -> szb
  // grid 3072 = 8 XCDs x 32 row-panels x 12 col-panels
  gemm128<1><<<3072, 256, 0, stream>>>(
      xnb, DM, wInB, DM, KDIM, 12, 32, nullptr, conv_w, conv_b, xcb, szb);

  // dbc = xc @ x_proj_w^T (rank-50, N pad 128): delta_raw -> dbcb, Bm/C -> bmc
  gemm32<3><<<256, 256, 0, stream>>>(
      xcb, DM, wXpB, DM, KDIM, 1, 32, bmc, nullptr, dbcb);

  // delta = softplus(dbc48 @ dt_proj_w^T + dt_b) -> bf16
  gemm32<2><<<1536, 256, 0, stream>>>(
      dbcb, 64, wDtB, 64, 64, 6, 32, nullptr, dt_proj_b, deltab);

  scan1_k<<<dim3(8, NC), 384, 0, stream>>>(deltab, xcb, bmc, A_log, aprod, hend);
  scan2_k<<<NCHAIN / 256, 256, 0, stream>>>(aprod, hend, carry);
  scan3_k<<<dim3(8, NC), 384, 0, stream>>>(deltab, xcb, bmc, A_log, Dp, szb, carry, ybf);

  // out = (y * silu(z)) @ out_proj_w^T; grid 1536 = 8 x 32 x 6
  gemm128<0><<<1536, 256, 0, stream>>>(
      ybf, DM, wOutB, DM, KDIM, 6, 32, out, nullptr, nullptr, nullptr, nullptr);
}